// Round 9
// baseline (1285.746 us; speedup 1.0000x reference)
//
#include <hip/hip_runtime.h>
#include <stdint.h>

typedef unsigned short u16;
typedef unsigned int u32;
typedef short bf16x8 __attribute__((ext_vector_type(8)));
typedef float f32x4 __attribute__((ext_vector_type(4)));

#define E_ 8
#define H_ 2048
#define F_ 4096
#define T_ 16384
#define TE_ 2048

#define WAITV(n) asm volatile("s_waitcnt vmcnt(" #n ")" ::: "memory")
#define BARF                       \
  do {                             \
    asm volatile("" ::: "memory"); \
    __builtin_amdgcn_s_barrier();  \
    asm volatile("" ::: "memory"); \
  } while (0)

__device__ __forceinline__ u16 f2bf(float f) {
  u32 u = __builtin_bit_cast(u32, f);
  u32 r = (u + 0x7FFFu + ((u >> 16) & 1u)) >> 16;  // RNE
  return (u16)r;
}

__device__ __forceinline__ void gload16(const u16* g, u16* l) {
  __builtin_amdgcn_global_load_lds(
      (__attribute__((address_space(1))) void*)g,
      (__attribute__((address_space(3))) void*)l, 16, 0, 0);
}

__device__ __forceinline__ void mfma_b(f32x4& acc, bf16x8 a, bf16x8 b) {
  asm volatile("v_mfma_f32_16x16x32_bf16 %0, %1, %2, %0"
               : "+v"(acc)
               : "v"(a), "v"(b));
}

__device__ __forceinline__ void cvt_f4(const float4* __restrict__ s4,
                                       uint2* __restrict__ d4, long i) {
  float4 v = s4[i];
  uint2 o;
  o.x = (u32)f2bf(v.x) | ((u32)f2bf(v.y) << 16);
  o.y = (u32)f2bf(v.z) | ((u32)f2bf(v.w) << 16);
  d4[i] = o;
}

// ---------- fp32 -> bf16 convert: two segments, one launch ----------
// Blocks [0,b0) handle segment 0 (x); blocks [b0,grid) handle segment 1
// (w_gate_up). Block-range split: no per-iteration segment branching.

__global__ __launch_bounds__(256) void cvt2_kernel(
    const float* __restrict__ s0, u16* __restrict__ d0, long n0,
    const float* __restrict__ s1, u16* __restrict__ d1, long n1, int b0) {
  if ((int)blockIdx.x < b0) {
    long i = (long)blockIdx.x * blockDim.x + threadIdx.x;
    long stride = (long)b0 * blockDim.x;
    const float4* s4 = (const float4*)s0;
    uint2* d4 = (uint2*)d0;
    for (; i < n0; i += stride) cvt_f4(s4, d4, i);
  } else {
    long i = (long)(blockIdx.x - b0) * blockDim.x + threadIdx.x;
    long stride = (long)(gridDim.x - b0) * blockDim.x;
    const float4* s4 = (const float4*)s1;
    uint2* d4 = (uint2*)d1;
    for (; i < n1; i += stride) cvt_f4(s4, d4, i);
  }
}

// ============ GEMM1 fused: hidden = silu(x@Wg^T) * (x@Wu^T) ============
// (round-7/8 proven: ~540us, MfmaUtil ~49, 0 conflicts)
// 256-thread / 4-wave blocks, tile 128 rows x 64 hidden cols, BK=64,
// ring-2 LDS = 64 KiB -> 2 blocks/CU (two independent barrier domains).
// Horizontal fusion: blocks with bx == gridDim.x-1 instead convert a
// 131072-float4 slice of w_down fp32->bf16 (needed only by gemm2, which
// launches later) using gemm1's idle HBM bandwidth.

__global__ __launch_bounds__(256, 2) void gemm1_silu(
    const u16* __restrict__ Xb, const u16* __restrict__ Wgu,
    u16* __restrict__ Hid, const float* __restrict__ WdnSrc,
    u16* __restrict__ WdnDst, long sX, long sW, long sH) {
  const int bx = blockIdx.x;
  if (bx == (int)gridDim.x - 1) {
    // cvt role: slice id from (y,z); 131072 float4 per slice
    const long cid = (long)blockIdx.z * gridDim.y + blockIdx.y;
    const long base = cid * 131072;
    const float4* s4 = (const float4*)WdnSrc;
    uint2* d4 = (uint2*)WdnDst;
    for (long i = base + threadIdx.x; i < base + 131072; i += 256)
      cvt_f4(s4, d4, i);
    return;
  }

  const int z = blockIdx.z;
  Xb += (long)z * sX;
  Wgu += (long)z * sW;
  Hid += (long)z * sH;

  const int by = blockIdx.y;  // row tile (128)
  const int tid = threadIdx.x;
  const int w = tid >> 6;  // 0..3
  const int lane = tid & 63;
  const int wr = w >> 1, wc = w & 1;
  const int fr = lane & 15, q = lane >> 4, l7 = lane & 7;

  // per-buf (16384 el = 32 KB): A[128][64] @0, Bg[64][64] @8192, Bu @12288
  __shared__ __attribute__((aligned(16))) u16 lds[2 * 16384];

  const int srow8 = lane >> 3;
  const int sgran = (lane & 7) ^ (lane >> 3);
  const u16* gA = Xb + (size_t)(by * 128 + srow8) * H_ + sgran * 8;
  const u16* gBg = Wgu + (size_t)(bx * 64 + srow8) * H_ + sgran * 8;
  const u16* gBu = gBg + (size_t)F_ * H_;

  auto stage = [&](int t, int buf) {
    u16* L = lds + buf * 16384;
    const int ko = t * 64;
#pragma unroll
    for (int i = 0; i < 4; ++i) {
      const int c = i * 4 + w;
      gload16(gA + (size_t)(c * 8) * H_ + ko, L + c * 512 + lane * 8);
    }
#pragma unroll
    for (int i = 0; i < 2; ++i) {
      const int c = i * 4 + w;
      gload16(gBg + (size_t)(c * 8) * H_ + ko, L + 8192 + c * 512 + lane * 8);
      gload16(gBu + (size_t)(c * 8) * H_ + ko, L + 12288 + c * 512 + lane * 8);
    }
  };

  f32x4 accG[4][2] = {};
  f32x4 accU[4][2] = {};

  auto comp = [&](int buf) {
    const u16* L = lds + buf * 16384;
#pragma unroll
    for (int ks = 0; ks < 2; ++ks) {
      const int seg = (((ks << 2) + q) ^ l7) << 3;
      bf16x8 a[4], bg[2], bu[2];
#pragma unroll
      for (int mi = 0; mi < 4; ++mi)
        a[mi] = *(const bf16x8*)&L[(wr * 64 + mi * 16 + fr) * 64 + seg];
#pragma unroll
      for (int ni = 0; ni < 2; ++ni) {
        bg[ni] = *(const bf16x8*)&L[8192 + (wc * 32 + ni * 16 + fr) * 64 + seg];
        bu[ni] =
            *(const bf16x8*)&L[12288 + (wc * 32 + ni * 16 + fr) * 64 + seg];
      }
      __builtin_amdgcn_s_setprio(1);
#pragma unroll
      for (int mi = 0; mi < 4; ++mi)
#pragma unroll
        for (int ni = 0; ni < 2; ++ni) {
          mfma_b(accG[mi][ni], a[mi], bg[ni]);
          mfma_b(accU[mi][ni], a[mi], bu[ni]);
        }
      __builtin_amdgcn_s_setprio(0);
    }
  };

  const int NT = H_ / 64;  // 32
  stage(0, 0);
  stage(1, 1);
  for (int t = 0; t < NT - 1; ++t) {
    WAITV(8);
    BARF;
    comp(t & 1);
    BARF;
    if (t + 2 < NT) stage(t + 2, t & 1);
  }
  WAITV(0);
  BARF;
  comp((NT - 1) & 1);

  const int row0 = by * 128 + wr * 64 + q * 4;
  const int col0 = bx * 64 + wc * 32 + fr;
#pragma unroll
  for (int mi = 0; mi < 4; ++mi)
#pragma unroll
    for (int ni = 0; ni < 2; ++ni)
#pragma unroll
      for (int j = 0; j < 4; ++j) {
        float g = accG[mi][ni][j];
        float u = accU[mi][ni][j];
        float h = (g / (1.f + __expf(-g))) * u;
        Hid[(size_t)(row0 + mi * 16 + j) * F_ + col0 + ni * 16] = f2bf(h);
      }
}

// ============ GEMM2: out = hidden @ w_down^T (fp32 out) ============
// (round-8 proven) m114 structure: 256-thread / 4-wave blocks, tile
// 128x128, wave tile 64x64, BK=64, ring-2 LDS = 64 KiB -> 2 blocks/CU.

__global__ __launch_bounds__(256, 2) void gemm2_down(
    const u16* __restrict__ Hd, const u16* __restrict__ Wd,
    float* __restrict__ Out, long sH, long sW, long sO) {
  const int z = blockIdx.z;
  Hd += (long)z * sH;
  Wd += (long)z * sW;
  Out += (long)z * sO;

  const int bx = blockIdx.x;  // H-col tile (128)
  const int by = blockIdx.y;  // row tile (128)
  const int tid = threadIdx.x;
  const int w = tid >> 6;  // 0..3
  const int lane = tid & 63;
  const int wr = w >> 1, wc = w & 1;
  const int fr = lane & 15, q = lane >> 4, l7 = lane & 7;

  // per-buf (16384 el = 32 KB): A[128][64] @0, B[128][64] @8192
  __shared__ __attribute__((aligned(16))) u16 lds[2 * 16384];

  const int srow8 = lane >> 3;
  const int sgran = (lane & 7) ^ (lane >> 3);
  const u16* gA = Hd + (size_t)(by * 128 + srow8) * F_ + sgran * 8;
  const u16* gB = Wd + (size_t)(bx * 128 + srow8) * F_ + sgran * 8;

  auto stage = [&](int t, int buf) {
    u16* L = lds + buf * 16384;
    const int ko = t * 64;
#pragma unroll
    for (int i = 0; i < 4; ++i) {
      const int c = i * 4 + w;
      gload16(gA + (size_t)(c * 8) * F_ + ko, L + c * 512 + lane * 8);
      gload16(gB + (size_t)(c * 8) * F_ + ko, L + 8192 + c * 512 + lane * 8);
    }
  };

  f32x4 acc[4][4] = {};

  auto comp = [&](int buf) {
    const u16* L = lds + buf * 16384;
#pragma unroll
    for (int ks = 0; ks < 2; ++ks) {
      const int seg = (((ks << 2) + q) ^ l7) << 3;
      bf16x8 a[4], b[4];
#pragma unroll
      for (int mi = 0; mi < 4; ++mi)
        a[mi] = *(const bf16x8*)&L[(wr * 64 + mi * 16 + fr) * 64 + seg];
#pragma unroll
      for (int ni = 0; ni < 4; ++ni)
        b[ni] = *(const bf16x8*)&L[8192 + (wc * 64 + ni * 16 + fr) * 64 + seg];
      __builtin_amdgcn_s_setprio(1);
#pragma unroll
      for (int mi = 0; mi < 4; ++mi)
#pragma unroll
        for (int ni = 0; ni < 4; ++ni) mfma_b(acc[mi][ni], a[mi], b[ni]);
      __builtin_amdgcn_s_setprio(0);
    }
  };

  const int NT = F_ / 64;  // 64
  stage(0, 0);
  stage(1, 1);
  for (int t = 0; t < NT - 1; ++t) {
    WAITV(8);
    BARF;
    comp(t & 1);
    BARF;
    if (t + 2 < NT) stage(t + 2, t & 1);
  }
  WAITV(0);
  BARF;
  comp((NT - 1) & 1);

  const int row0 = by * 128 + wr * 64 + q * 4;
  const int col0 = bx * 128 + wc * 64 + fr;
#pragma unroll
  for (int mi = 0; mi < 4; ++mi)
#pragma unroll
    for (int ni = 0; ni < 4; ++ni)
#pragma unroll
      for (int j = 0; j < 4; ++j)
        Out[(size_t)(row0 + mi * 16 + j) * H_ + col0 + ni * 16] =
            acc[mi][ni][j];
}

// ---------- host ----------

extern "C" void kernel_launch(void* const* d_in, const int* in_sizes, int n_in,
                              void* d_out, int out_size, void* d_ws,
                              size_t ws_size, hipStream_t stream) {
  (void)in_sizes;
  (void)n_in;
  (void)out_size;
  const float* x = (const float*)d_in[0];
  const float* wgu = (const float*)d_in[1];
  const float* wdn = (const float*)d_in[2];
  float* out = (float*)d_out;
  u16* ws = (u16*)d_ws;

  const size_t xbN = (size_t)T_ * H_;
  const size_t wguN = (size_t)E_ * 2 * F_ * H_;
  const size_t wdnN = (size_t)E_ * H_ * F_;
  const size_t hidN = (size_t)T_ * F_;
  const size_t fullBytes = (xbN + wguN + wdnN + hidN) * 2;  // 576 MiB

  dim3 cblk(256), gblk(256);

  if (ws_size >= fullBytes) {
    u16* xb = ws;
    u16* wgub = xb + xbN;
    u16* wdnb = wgub + wguN;
    u16* hid = wdnb + wdnN;
    // one launch: x (blocks [0,832)) + w_gate_up (blocks [832,4096))
    cvt2_kernel<<<4096, cblk, 0, stream>>>(x, xb, (long)(xbN / 4), wgu, wgub,
                                           (long)(wguN / 4), 832);
    // gemm1 + fused w_down cvt (extra bx column; 16*8=128 slices * 131072
    // float4 = wdnN/4 exactly)
    gemm1_silu<<<dim3(F_ / 64 + 1, TE_ / 128, E_), gblk, 0, stream>>>(
        xb, wgub, hid, wdn, wdnb, (long)TE_ * H_, (long)2 * F_ * H_,
        (long)TE_ * F_);
    gemm2_down<<<dim3(H_ / 128, TE_ / 128, E_), gblk, 0, stream>>>(
        hid, wdnb, out, (long)TE_ * F_, (long)H_ * F_, (long)TE_ * H_);
  } else {
    u16* xb = ws;
    u16* wgub = xb + (size_t)TE_ * H_;
    u16* wdnb = wgub + (size_t)2 * F_ * H_;
    u16* hid = wdnb + (size_t)H_ * F_;
    for (int e = 0; e < E_; ++e) {
      cvt2_kernel<<<2048, cblk, 0, stream>>>(
          x + (size_t)e * TE_ * H_, xb, (long)((size_t)TE_ * H_ / 4),
          wgu + (size_t)e * 2 * F_ * H_, wgub,
          (long)((size_t)2 * F_ * H_ / 4), 410);
      // per-expert: 16*1=16 cvt slices * 131072 float4 = H_*F_/4 exactly
      gemm1_silu<<<dim3(F_ / 64 + 1, TE_ / 128, 1), gblk, 0, stream>>>(
          xb, wgub, hid, wdn + (size_t)e * H_ * F_, wdnb, 0, 0, 0);
      gemm2_down<<<dim3(H_ / 128, TE_ / 128, 1), gblk, 0, stream>>>(
          hid, wdnb, out + (size_t)e * TE_ * H_, 0, 0, 0);
    }
  }
}